// Round 12
// baseline (62.183 us; speedup 1.0000x reference)
//
#include <hip/hip_runtime.h>
#include <hip/hip_bf16.h>

// AdLIF SNN forward, MI355X. B=512, T=500, NIN=96, H=512, NOUT=2.
//
// Round-12: TWO batch rows per block, grid=256 (one block per CU).
//  - Halves the serial phase count (was 2 sequential block-rounds of 8).
//  - Two independent scan pipelines per wave (rows A,B) -> 2x ILP to hide
//    ds_read / MFMA / fma-chain latency at 8 waves/CU.
//  - W1 fragment prologue amortized across both rows.
// Everything else is the validated register-scan scheme (rounds 7-11):
//  - x staged in LDS bf16, TIME-PERMUTED rows (row s*16+4q+j holds
//    t_local=16q+4s+j): after 4 subtile MFMAs lane quad lq holds 16
//    consecutive timesteps per owned h.
//  - Fold: d = fma(al, d, acc) x16/segment + running max, in registers.
//  - Deferred compose: phase q composes chunk q-1 (shfl_xor(16/32) + al^16
//    chain) while fold(q) is in flight. flag(q-1) set in phase q, read at
//    top of q+1, acted on at its end.
//  - Spike spec: no spike => a==0,spk==0; trip = max_seg(d)+|v_seg_start|>1
//    (sound). Cold path: rollback to per-row 2-slot checkpoint, exact
//    re-run (identity restage, I tiles in LDS overlay, full Wrec
//    recurrence) for BOTH rows (exact==speculative for non-spiking row).
//  - Partial chunk 7 (52 steps): zero-fill + exact al^-12 correction.
// Cold-path I buffer overlays xlds[1] (cold only stages x in xlds[0][0]).

#define B2_ 256
#define T_ 500
#define NIN_ 96
#define H_ 512
#define CH 64
#define NPH 8
#define LASTN 52
#define XPAD 104        // shorts per x row (208 B pitch)
#define PTC 24          // cold-path I pitch (shorts)

typedef __attribute__((ext_vector_type(8))) short bf16x8;  // 8 bf16 = 4 VGPR
typedef __attribute__((ext_vector_type(4))) float f32x4;

__device__ __forceinline__ unsigned short f2bf(float f) {   // RNE (W1, cold I)
    union { __hip_bfloat16 h; unsigned short s; } u;
    u.h = __float2bfloat16(f);
    return u.s;
}
__device__ __forceinline__ unsigned pk2(float lo, float hi) {
    return (unsigned)f2bf(lo) | ((unsigned)f2bf(hi) << 16);
}
// truncating pack: [bf16(lo), bf16(hi)] in one v_perm_b32
__device__ __forceinline__ unsigned pk2t(float lo, float hi) {
    return __builtin_amdgcn_perm(__float_as_uint(hi), __float_as_uint(lo),
                                 0x07060302u);
}
__device__ __forceinline__ bf16x8 packw(const float* p, float om) {
    float4 u0 = *reinterpret_cast<const float4*>(p);
    float4 u1 = *reinterpret_cast<const float4*>(p + 4);
    union { unsigned d[4]; bf16x8 v8; } pk;
    pk.d[0] = pk2(om * u0.x, om * u0.y);
    pk.d[1] = pk2(om * u0.z, om * u0.w);
    pk.d[2] = pk2(om * u1.x, om * u1.y);
    pk.d[3] = pk2(om * u1.z, om * u1.w);
    return pk.v8;
}
__device__ __forceinline__ float pow16(float a) {
    float a2 = a * a, a4 = a2 * a2, a8 = a4 * a4;
    return a8 * a8;
}

// Exact AdLIF cold path. Irow holds I' = oma*I (bf16, oma folded in).
__device__ __noinline__ void exact_steps(
    int nsteps, const unsigned short* Irow, float* spk_lds,
    const float* __restrict__ Wrec, int tid,
    float al, float oma, float rh, float be,
    float& v, float& a, float& spk)
{
    for (int tt = 0; tt < nsteps; ++tt) {
        float Ip = __uint_as_float(((unsigned)Irow[tt]) << 16);
        float racc = 0.f;
        for (int hp = 0; hp < H_; ++hp) {
            if (spk_lds[hp] != 0.f) racc += Wrec[(size_t)tid * H_ + hp];
        }
        float vnew = (al * v) * (1.f - spk) + Ip + oma * (racc - a);
        spk = (vnew - 1.f) > 0.f ? 1.f : 0.f;
        a = fmaf(be, spk, rh * a);
        v = vnew;
        __syncthreads();
        spk_lds[tid] = spk;
        __syncthreads();
    }
}

__global__ __launch_bounds__(512, 2) void snn_dual(
    const float* __restrict__ x,      // [B, T, NIN]
    const float* __restrict__ W1,     // [H, NIN]
    const float* __restrict__ Wrec,   // [H, H]
    const float* __restrict__ W2,     // [2, H]
    const float* __restrict__ alpha,  // [H]
    const float* __restrict__ rho,    // [H]
    const float* __restrict__ beta_a, // [H]
    float* __restrict__ out)          // [B, 2]
{
    const int b2   = blockIdx.x;     // rows 2*b2, 2*b2+1
    const int tid  = threadIdx.x;
    const int wv   = tid >> 6;
    const int lane = tid & 63;
    const int lq   = lane >> 4;
    const int lr   = lane & 15;

    __shared__ __align__(16) unsigned short xlds[2][2][CH * XPAD]; // 53.2 KB
    __shared__ float spk_lds[H_];
    __shared__ int   flagLds[8];   // (chunk j -> slot j&3) * 2 + row
    __shared__ float red[16];
    unsigned short* Icold = &xlds[1][0][0];   // cold-path overlay (24 KB)

    // --- W1 fragments, NAMED, oma = 1-alpha folded in. Wave owns 4 h-tiles.
    bf16x8 wf00, wf01, wf02, wf10, wf11, wf12,
           wf20, wf21, wf22, wf30, wf31, wf32;
    float al0, al1, al2, al3, k0, k1, k2, k3;
#define LOADW(I, WA, WB, WC, ALV, KV) { \
    const int h_ = wv * 64 + (I) * 16 + lr; \
    const float av_ = alpha[h_]; ALV = av_; KV = pow16(av_); \
    const float om_ = 1.0f - av_; \
    const float* wr_ = W1 + h_ * NIN_ + lq * 8; \
    WA = packw(wr_, om_); WB = packw(wr_ + 32, om_); WC = packw(wr_ + 64, om_); }
    LOADW(0, wf00, wf01, wf02, al0, k0)
    LOADW(1, wf10, wf11, wf12, al1, k1)
    LOADW(2, wf20, wf21, wf22, al2, k2)
    LOADW(3, wf30, wf31, wf32, al3, k3)
#undef LOADW

    // x staging: all 512 threads; thread covers t_local = st, 12 floats/row.
    const float4* xb4A = reinterpret_cast<const float4*>(x + (size_t)(2 * b2)     * T_ * NIN_);
    const float4* xb4B = reinterpret_cast<const float4*>(x + (size_t)(2 * b2 + 1) * T_ * NIN_);
    const int st = tid >> 3, sq = tid & 7;
    // time-permuted row: row s*16+4q+j holds t_local = 16q+4s+j
    const int rwPerm = ((st & 15) >> 2) * 16 + (st >> 4) * 4 + (st & 3);
    float4 xrA0, xrA1, xrA2, xrB0, xrB1, xrB2;
    auto XLOADA = [&](int c) {
        int t = c * CH + st;
        if (t < T_) {
            const float4* p = xb4A + t * 24 + sq * 3;
            xrA0 = p[0]; xrA1 = p[1]; xrA2 = p[2];
        } else {
            xrA0 = make_float4(0.f, 0.f, 0.f, 0.f); xrA1 = xrA0; xrA2 = xrA0;
        }
    };
    auto XLOADB = [&](int c) {
        int t = c * CH + st;
        if (t < T_) {
            const float4* p = xb4B + t * 24 + sq * 3;
            xrB0 = p[0]; xrB1 = p[1]; xrB2 = p[2];
        } else {
            xrB0 = make_float4(0.f, 0.f, 0.f, 0.f); xrB1 = xrB0; xrB2 = xrB0;
        }
    };
    auto XWRITEA = [&](int buf, int row) {
        unsigned short* base = &xlds[buf][0][row * XPAD + sq * 12];
        *reinterpret_cast<uint2*>(base)     = make_uint2(pk2t(xrA0.x, xrA0.y), pk2t(xrA0.z, xrA0.w));
        *reinterpret_cast<uint2*>(base + 4) = make_uint2(pk2t(xrA1.x, xrA1.y), pk2t(xrA1.z, xrA1.w));
        *reinterpret_cast<uint2*>(base + 8) = make_uint2(pk2t(xrA2.x, xrA2.y), pk2t(xrA2.z, xrA2.w));
    };
    auto XWRITEB = [&](int buf, int row) {
        unsigned short* base = &xlds[buf][1][row * XPAD + sq * 12];
        *reinterpret_cast<uint2*>(base)     = make_uint2(pk2t(xrB0.x, xrB0.y), pk2t(xrB0.z, xrB0.w));
        *reinterpret_cast<uint2*>(base + 4) = make_uint2(pk2t(xrB1.x, xrB1.y), pk2t(xrB1.z, xrB1.w));
        *reinterpret_cast<uint2*>(base + 8) = make_uint2(pk2t(xrB2.x, xrB2.y), pk2t(xrB2.z, xrB2.w));
    };

    // per-row scan state
    float vA0 = 0.f, vA1 = 0.f, vA2 = 0.f, vA3 = 0.f;
    float vB0 = 0.f, vB1 = 0.f, vB2 = 0.f, vB3 = 0.f;
    float cAe0=0.f,cAe1=0.f,cAe2=0.f,cAe3=0.f, cAo0=0.f,cAo1=0.f,cAo2=0.f,cAo3=0.f;
    float cBe0=0.f,cBe1=0.f,cBe2=0.f,cBe3=0.f, cBo0=0.f,cBo1=0.f,cBo2=0.f,cBo3=0.f;
    float dA0=0.f,dA1=0.f,dA2=0.f,dA3=0.f, mA0=0.f,mA1=0.f,mA2=0.f,mA3=0.f;
    float dB0=0.f,dB1=0.f,dB2=0.f,dB3=0.f, mB0=0.f,mB1=0.f,mB2=0.f,mB3=0.f;

    if (tid < 8) flagLds[tid] = 0;
    XLOADA(0); XLOADB(0); XWRITEA(0, rwPerm); XWRITEB(0, rwPerm);
    XLOADA(1); XLOADB(1);
    __syncthreads();

    int coldF = -1;
    const bool bb0 = (lq & 1) != 0, bb1 = (lq & 2) != 0;

#define COMPOSE(DV, MV, ALV, KV, VV, TRIP) { \
        float A_  = DV; \
        float B_v = __shfl_xor(A_, 16); \
        float C_v = __shfl_xor(A_, 32); \
        float D_v = __shfl_xor(B_v, 32); \
        float x0_ = bb0 ? B_v : A_;  float x1_ = bb0 ? A_  : B_v; \
        float x2_ = bb0 ? D_v : C_v; float x3_ = bb0 ? C_v : D_v; \
        float e0_ = bb1 ? x2_ : x0_; float e1_ = bb1 ? x3_ : x1_; \
        float e2_ = bb1 ? x0_ : x2_; float e3_ = bb1 ? x1_ : x3_; \
        float w1_ = fmaf(KV, VV, e0_);  float w2_ = fmaf(KV, w1_, e1_); \
        float w3_ = fmaf(KV, w2_, e2_); float w4_ = fmaf(KV, w3_, e3_); \
        float vs_ = (lq == 0) ? VV : (lq == 1) ? w1_ : (lq == 2) ? w2_ : w3_; \
        TRIP = TRIP || ((MV + fabsf(vs_)) > 1.0f); \
        VV = w4_; }

#define MFMA_(XF, WA, WB, WC, WD) \
        a0 = __builtin_amdgcn_mfma_f32_16x16x32_bf16(XF, WA, a0, 0, 0, 0); \
        a1 = __builtin_amdgcn_mfma_f32_16x16x32_bf16(XF, WB, a1, 0, 0, 0); \
        a2 = __builtin_amdgcn_mfma_f32_16x16x32_bf16(XF, WC, a2, 0, 0, 0); \
        a3 = __builtin_amdgcn_mfma_f32_16x16x32_bf16(XF, WD, a3, 0, 0, 0);
#define FOLD_(AV, ALV, DV, MV) \
        DV = fmaf(ALV, DV, AV[0]); MV = fmaxf(MV, DV); \
        DV = fmaf(ALV, DV, AV[1]); MV = fmaxf(MV, DV); \
        DV = fmaf(ALV, DV, AV[2]); MV = fmaxf(MV, DV); \
        DV = fmaf(ALV, DV, AV[3]); MV = fmaxf(MV, DV);
#define SUBTILE(S, XB, D0,D1,D2,D3, M0,M1,M2,M3) { \
        f32x4 a0 = {0.f,0.f,0.f,0.f}, a1 = a0, a2 = a0, a3 = a0; \
        { bf16x8 xf = *reinterpret_cast<const bf16x8*>( \
              &(XB)[((S) * 16 + lr) * XPAD +  0 + lq * 8]); \
          MFMA_(xf, wf00, wf10, wf20, wf30) } \
        { bf16x8 xf = *reinterpret_cast<const bf16x8*>( \
              &(XB)[((S) * 16 + lr) * XPAD + 32 + lq * 8]); \
          MFMA_(xf, wf01, wf11, wf21, wf31) } \
        { bf16x8 xf = *reinterpret_cast<const bf16x8*>( \
              &(XB)[((S) * 16 + lr) * XPAD + 64 + lq * 8]); \
          MFMA_(xf, wf02, wf12, wf22, wf32) } \
        FOLD_(a0, al0, D0, M0) FOLD_(a1, al1, D1, M1) \
        FOLD_(a2, al2, D2, M2) FOLD_(a3, al3, D3, M3) }

    #pragma unroll 1
    for (int q = 0; q < NPH; ++q) {
        // flag(q-2): set during phase q-1, visible now. Read early, act late.
        int f = 0;
        if (q >= 2) {
            f = flagLds[((q - 2) & 3) * 2] | flagLds[((q - 2) & 3) * 2 + 1];
            if (tid == 0) {
                flagLds[((q - 2) & 3) * 2] = 0;
                flagLds[((q - 2) & 3) * 2 + 1] = 0;
            }
        }
        // checkpoint: v here == v_start(q-1) -> slot (q-1)&1
        if (((q - 1) & 1) == 0) {
            cAe0 = vA0; cAe1 = vA1; cAe2 = vA2; cAe3 = vA3;
            cBe0 = vB0; cBe1 = vB1; cBe2 = vB2; cBe3 = vB3;
        } else {
            cAo0 = vA0; cAo1 = vA1; cAo2 = vA2; cAo3 = vA3;
            cBo0 = vB0; cBo1 = vB1; cBo2 = vB2; cBo3 = vB3;
        }

        // --- compose chunk q-1, both rows.
        if (q >= 1) {
            bool tripA = false, tripB = false;
            COMPOSE(dA0, mA0, al0, k0, vA0, tripA)
            COMPOSE(dB0, mB0, al0, k0, vB0, tripB)
            COMPOSE(dA1, mA1, al1, k1, vA1, tripA)
            COMPOSE(dB1, mB1, al1, k1, vB1, tripB)
            COMPOSE(dA2, mA2, al2, k2, vA2, tripA)
            COMPOSE(dB2, mB2, al2, k2, vB2, tripB)
            COMPOSE(dA3, mA3, al3, k3, vA3, tripA)
            COMPOSE(dB3, mB3, al3, k3, vB3, tripB)
            if (tripA) flagLds[((q - 1) & 3) * 2] = 1;       // benign race
            if (tripB) flagLds[((q - 1) & 3) * 2 + 1] = 1;
        }

        // --- fold chunk q, both rows (independent chains interleaved).
        dA0 = 0.f; dA1 = 0.f; dA2 = 0.f; dA3 = 0.f;
        dB0 = 0.f; dB1 = 0.f; dB2 = 0.f; dB3 = 0.f;
        mA0 = -3.4e38f; mA1 = -3.4e38f; mA2 = -3.4e38f; mA3 = -3.4e38f;
        mB0 = -3.4e38f; mB1 = -3.4e38f; mB2 = -3.4e38f; mB3 = -3.4e38f;
        const unsigned short* xbA = xlds[q & 1][0];
        const unsigned short* xbB = xlds[q & 1][1];
        SUBTILE(0, xbA, dA0,dA1,dA2,dA3, mA0,mA1,mA2,mA3)
        SUBTILE(0, xbB, dB0,dB1,dB2,dB3, mB0,mB1,mB2,mB3)
        SUBTILE(1, xbA, dA0,dA1,dA2,dA3, mA0,mA1,mA2,mA3)
        SUBTILE(1, xbB, dB0,dB1,dB2,dB3, mB0,mB1,mB2,mB3)
        SUBTILE(2, xbA, dA0,dA1,dA2,dA3, mA0,mA1,mA2,mA3)
        SUBTILE(2, xbB, dB0,dB1,dB2,dB3, mB0,mB1,mB2,mB3)
        SUBTILE(3, xbA, dA0,dA1,dA2,dA3, mA0,mA1,mA2,mA3)
        SUBTILE(3, xbB, dB0,dB1,dB2,dB3, mB0,mB1,mB2,mB3)

        if (q + 1 < NPH) { XWRITEA((q + 1) & 1, rwPerm); XWRITEB((q + 1) & 1, rwPerm); }
        if (q + 2 < NPH) { XLOADA(q + 2); XLOADB(q + 2); }

        if (f) { coldF = q - 2; break; }   // uniform; phase q was speculative
        __syncthreads();                   // xlds[(q+1)&1] + flag(q-1) visible
    }

    // --- epilogue: chunks NPH-2 (flag set in phase NPH-1) and NPH-1.
    if (coldF < 0 &&
        (flagLds[((NPH - 2) & 3) * 2] | flagLds[((NPH - 2) & 3) * 2 + 1]) != 0)
        coldF = NPH - 2;
    if (coldF < 0) {
        // checkpoint v_start(NPH-1) -> slot (NPH-1)&1 (odd)
        cAo0 = vA0; cAo1 = vA1; cAo2 = vA2; cAo3 = vA3;
        cBo0 = vB0; cBo1 = vB1; cBo2 = vB2; cBo3 = vB3;
        bool tripA = false, tripB = false;
        COMPOSE(dA0, mA0, al0, k0, vA0, tripA)
        COMPOSE(dB0, mB0, al0, k0, vB0, tripB)
        COMPOSE(dA1, mA1, al1, k1, vA1, tripA)
        COMPOSE(dB1, mB1, al1, k1, vB1, tripB)
        COMPOSE(dA2, mA2, al2, k2, vA2, tripA)
        COMPOSE(dB2, mB2, al2, k2, vB2, tripB)
        COMPOSE(dA3, mA3, al3, k3, vA3, tripA)
        COMPOSE(dB3, mB3, al3, k3, vB3, tripB)
        // last chunk had 12 zero-input (decay-only) steps: * al^-12
        { float q2 = al0*al0, q4 = q2*q2; float c = q4 / k0; vA0 *= c; vB0 *= c; }
        { float q2 = al1*al1, q4 = q2*q2; float c = q4 / k1; vA1 *= c; vB1 *= c; }
        { float q2 = al2*al2, q4 = q2*q2; float c = q4 / k2; vA2 *= c; vB2 *= c; }
        { float q2 = al3*al3, q4 = q2*q2; float c = q4 / k3; vA3 *= c; vB3 *= c; }
        if (tripA) flagLds[((NPH - 1) & 3) * 2] = 1;
        if (tripB) flagLds[((NPH - 1) & 3) * 2 + 1] = 1;
        __syncthreads();
        if ((flagLds[((NPH - 1) & 3) * 2] | flagLds[((NPH - 1) & 3) * 2 + 1]) != 0)
            coldF = NPH - 1;
    }
#undef COMPOSE

    bool ex = false;
    float vexA = 0.f, vexB = 0.f;
    if (coldF >= 0) {
        // rollback BOTH rows to v_start(coldF) (slot coldF&1); a,spk == 0.
        // Exact re-run == speculative for a non-spiking row, so this is
        // correct even if only one row tripped.
        float vvA, vvB;
        if (coldF & 1) {
            vvA = (lq==0)?cAo0:(lq==1)?cAo1:(lq==2)?cAo2:cAo3;
            vvB = (lq==0)?cBo0:(lq==1)?cBo1:(lq==2)?cBo2:cBo3;
        } else {
            vvA = (lq==0)?cAe0:(lq==1)?cAe1:(lq==2)?cAe2:cAe3;
            vvB = (lq==0)?cBe0:(lq==1)?cBe1:(lq==2)?cBe2:cBe3;
        }
        const float alc  = alpha[tid];
        const float omac = 1.0f - alc;
        const float rhc  = rho[tid];
        const float bec  = beta_a[tid];
        #pragma unroll 1
        for (int row = 0; row < 2; ++row) {
            float vv = row ? vvB : vvA;
            float aa = 0.f, ss = 0.f;
            __syncthreads();
            spk_lds[tid] = 0.f;
            #pragma unroll 1
            for (int jj = coldF; jj < NPH; ++jj) {
                __syncthreads();
                if (row) { XLOADB(jj); } else { XLOADA(jj); }
                // identity-row restage of this row's x into xlds[0][0]
                {
                    unsigned short* base = &xlds[0][0][st * XPAD + sq * 12];
                    float4 r0 = row ? xrB0 : xrA0;
                    float4 r1 = row ? xrB1 : xrA1;
                    float4 r2 = row ? xrB2 : xrA2;
                    *reinterpret_cast<uint2*>(base)     = make_uint2(pk2t(r0.x, r0.y), pk2t(r0.z, r0.w));
                    *reinterpret_cast<uint2*>(base + 4) = make_uint2(pk2t(r1.x, r1.y), pk2t(r1.z, r1.w));
                    *reinterpret_cast<uint2*>(base + 8) = make_uint2(pk2t(r2.x, r2.y), pk2t(r2.z, r2.w));
                }
                __syncthreads();
                int remain = (jj == NPH - 1) ? LASTN : CH;
                #pragma unroll 1
                for (int s = 0; s < 4 && remain > 0; ++s) {
                    f32x4 c0 = {0.f,0.f,0.f,0.f}, c1 = c0, c2 = c0, c3 = c0;
                    #pragma unroll
                    for (int kb = 0; kb < 3; ++kb) {
                        bf16x8 xf = *reinterpret_cast<const bf16x8*>(
                            &xlds[0][0][(s * 16 + lr) * XPAD + kb * 32 + lq * 8]);
                        if (kb == 0) {
                            c0 = __builtin_amdgcn_mfma_f32_16x16x32_bf16(xf, wf00, c0, 0, 0, 0);
                            c1 = __builtin_amdgcn_mfma_f32_16x16x32_bf16(xf, wf10, c1, 0, 0, 0);
                            c2 = __builtin_amdgcn_mfma_f32_16x16x32_bf16(xf, wf20, c2, 0, 0, 0);
                            c3 = __builtin_amdgcn_mfma_f32_16x16x32_bf16(xf, wf30, c3, 0, 0, 0);
                        } else if (kb == 1) {
                            c0 = __builtin_amdgcn_mfma_f32_16x16x32_bf16(xf, wf01, c0, 0, 0, 0);
                            c1 = __builtin_amdgcn_mfma_f32_16x16x32_bf16(xf, wf11, c1, 0, 0, 0);
                            c2 = __builtin_amdgcn_mfma_f32_16x16x32_bf16(xf, wf21, c2, 0, 0, 0);
                            c3 = __builtin_amdgcn_mfma_f32_16x16x32_bf16(xf, wf31, c3, 0, 0, 0);
                        } else {
                            c0 = __builtin_amdgcn_mfma_f32_16x16x32_bf16(xf, wf02, c0, 0, 0, 0);
                            c1 = __builtin_amdgcn_mfma_f32_16x16x32_bf16(xf, wf12, c1, 0, 0, 0);
                            c2 = __builtin_amdgcn_mfma_f32_16x16x32_bf16(xf, wf22, c2, 0, 0, 0);
                            c3 = __builtin_amdgcn_mfma_f32_16x16x32_bf16(xf, wf32, c3, 0, 0, 0);
                        }
                    }
                    const int h0 = wv * 64 + lr;
                    *reinterpret_cast<uint2*>(&Icold[(h0     ) * PTC + lq * 4]) =
                        make_uint2(pk2(c0[0], c0[1]), pk2(c0[2], c0[3]));
                    *reinterpret_cast<uint2*>(&Icold[(h0 + 16) * PTC + lq * 4]) =
                        make_uint2(pk2(c1[0], c1[1]), pk2(c1[2], c1[3]));
                    *reinterpret_cast<uint2*>(&Icold[(h0 + 32) * PTC + lq * 4]) =
                        make_uint2(pk2(c2[0], c2[1]), pk2(c2[2], c2[3]));
                    *reinterpret_cast<uint2*>(&Icold[(h0 + 48) * PTC + lq * 4]) =
                        make_uint2(pk2(c3[0], c3[1]), pk2(c3[2], c3[3]));
                    __syncthreads();
                    int ns = remain < 16 ? remain : 16;
                    exact_steps(ns, &Icold[tid * PTC], spk_lds, Wrec, tid,
                                alc, omac, rhc, bec, vv, aa, ss);
                    remain -= ns;
                }
            }
            if (row) vexB = vv; else vexA = vv;
        }
        ex = true;
    }

    // Readout: out[b,n] = sum_h v_h * W2[n,h], rows A then B.
    #pragma unroll 1
    for (int row = 0; row < 2; ++row) {
        float p0, p1;
        if (ex) {
            float vex = row ? vexB : vexA;
            p0 = vex * W2[tid];
            p1 = vex * W2[H_ + tid];
        } else {
            p0 = 0.f; p1 = 0.f;
            if (lq == 0) {   // v replicated over lq; count each h once
                const int h0 = wv * 64 + lr;
                float u0 = row ? vB0 : vA0, u1 = row ? vB1 : vA1;
                float u2 = row ? vB2 : vA2, u3 = row ? vB3 : vA3;
                p0 = u0 * W2[h0]      + u1 * W2[h0 + 16]
                   + u2 * W2[h0 + 32] + u3 * W2[h0 + 48];
                p1 = u0 * W2[H_ + h0]      + u1 * W2[H_ + h0 + 16]
                   + u2 * W2[H_ + h0 + 32] + u3 * W2[H_ + h0 + 48];
            }
        }
        #pragma unroll
        for (int off = 32; off > 0; off >>= 1) {
            p0 += __shfl_down(p0, off, 64);
            p1 += __shfl_down(p1, off, 64);
        }
        __syncthreads();   // red[] free (prev row's readout done)
        if (lane == 0) { red[wv * 2] = p0; red[wv * 2 + 1] = p1; }
        __syncthreads();
        if (tid == 0) {
            float s0 = 0.f, s1 = 0.f;
            #pragma unroll
            for (int w8 = 0; w8 < 8; ++w8) { s0 += red[w8 * 2]; s1 += red[w8 * 2 + 1]; }
            out[(2 * b2 + row) * 2 + 0] = s0;
            out[(2 * b2 + row) * 2 + 1] = s1;
        }
    }
}

extern "C" void kernel_launch(void* const* d_in, const int* in_sizes, int n_in,
                              void* d_out, int out_size, void* d_ws, size_t ws_size,
                              hipStream_t stream) {
    const float* x      = (const float*)d_in[0];
    const float* W1     = (const float*)d_in[1];
    const float* Wrec   = (const float*)d_in[2];
    const float* W2     = (const float*)d_in[3];
    const float* alpha  = (const float*)d_in[4];
    const float* rho    = (const float*)d_in[5];
    const float* beta_a = (const float*)d_in[6];
    float* out = (float*)d_out;

    snn_dual<<<dim3(B2_), dim3(512), 0, stream>>>(
        x, W1, Wrec, W2, alpha, rho, beta_a, out);
}

// Round 13
// 62.092 us; speedup vs baseline: 1.0015x; 1.0015x over previous
//
#include <hip/hip_runtime.h>
#include <hip/hip_bf16.h>

// AdLIF SNN forward, MI355X. B=512, T=500, NIN=96, H=512, NOUT=2.
//
// Round-13 = round-12 dual-row kernel with __launch_bounds__(512, 1).
// Round 12's (512,2) imposed a 128-VGPR cap on a ~180-reg dual-row state
// -> ~45 regs spilled (VGPR_Count=128 pinned at cap, WRITE_SIZE 45 MB).
// Grid is 256 = one block per CU BY DESIGN, so (512,1) (256-VGPR cap)
// costs nothing and eliminates the spill.
//
// Design (validated rounds 7-12, absmax <= 9.8e-4):
//  - TWO batch rows per block, grid=256: halves serial phase depth and
//    gives each wave two independent scan pipelines (ILP) to hide
//    ds_read/MFMA/fma-chain latency at 2 waves/SIMD.
//  - x staged in LDS bf16, TIME-PERMUTED rows (row s*16+4q+j holds
//    t_local=16q+4s+j): after 4 subtile MFMAs lane quad lq holds 16
//    consecutive timesteps per owned h.
//  - Fold: d = fma(al, d, acc) x16/segment + running max, in registers.
//  - Deferred compose: phase q composes chunk q-1 (shfl_xor(16/32) + al^16
//    chain) while fold(q) is in flight; flag(q-1) set in phase q, read at
//    top of q+1, acted on at its end.
//  - Spike spec: no spike => a==0,spk==0; trip = max_seg(d)+|v_seg_start|>1
//    (sound). Cold path: rollback to per-row 2-slot checkpoint, exact
//    re-run (identity restage, I tiles in LDS overlay, full Wrec
//    recurrence) for BOTH rows.
//  - Partial chunk 7 (52 steps): zero-fill + exact al^-12 correction.

#define B2_ 256
#define T_ 500
#define NIN_ 96
#define H_ 512
#define CH 64
#define NPH 8
#define LASTN 52
#define XPAD 104        // shorts per x row (208 B pitch)
#define PTC 24          // cold-path I pitch (shorts)

typedef __attribute__((ext_vector_type(8))) short bf16x8;  // 8 bf16 = 4 VGPR
typedef __attribute__((ext_vector_type(4))) float f32x4;

__device__ __forceinline__ unsigned short f2bf(float f) {   // RNE (W1, cold I)
    union { __hip_bfloat16 h; unsigned short s; } u;
    u.h = __float2bfloat16(f);
    return u.s;
}
__device__ __forceinline__ unsigned pk2(float lo, float hi) {
    return (unsigned)f2bf(lo) | ((unsigned)f2bf(hi) << 16);
}
// truncating pack: [bf16(lo), bf16(hi)] in one v_perm_b32
__device__ __forceinline__ unsigned pk2t(float lo, float hi) {
    return __builtin_amdgcn_perm(__float_as_uint(hi), __float_as_uint(lo),
                                 0x07060302u);
}
__device__ __forceinline__ bf16x8 packw(const float* p, float om) {
    float4 u0 = *reinterpret_cast<const float4*>(p);
    float4 u1 = *reinterpret_cast<const float4*>(p + 4);
    union { unsigned d[4]; bf16x8 v8; } pk;
    pk.d[0] = pk2(om * u0.x, om * u0.y);
    pk.d[1] = pk2(om * u0.z, om * u0.w);
    pk.d[2] = pk2(om * u1.x, om * u1.y);
    pk.d[3] = pk2(om * u1.z, om * u1.w);
    return pk.v8;
}
__device__ __forceinline__ float pow16(float a) {
    float a2 = a * a, a4 = a2 * a2, a8 = a4 * a4;
    return a8 * a8;
}

// Exact AdLIF cold path. Irow holds I' = oma*I (bf16, oma folded in).
__device__ __noinline__ void exact_steps(
    int nsteps, const unsigned short* Irow, float* spk_lds,
    const float* __restrict__ Wrec, int tid,
    float al, float oma, float rh, float be,
    float& v, float& a, float& spk)
{
    for (int tt = 0; tt < nsteps; ++tt) {
        float Ip = __uint_as_float(((unsigned)Irow[tt]) << 16);
        float racc = 0.f;
        for (int hp = 0; hp < H_; ++hp) {
            if (spk_lds[hp] != 0.f) racc += Wrec[(size_t)tid * H_ + hp];
        }
        float vnew = (al * v) * (1.f - spk) + Ip + oma * (racc - a);
        spk = (vnew - 1.f) > 0.f ? 1.f : 0.f;
        a = fmaf(be, spk, rh * a);
        v = vnew;
        __syncthreads();
        spk_lds[tid] = spk;
        __syncthreads();
    }
}

__global__ __launch_bounds__(512, 1) void snn_dual2(
    const float* __restrict__ x,      // [B, T, NIN]
    const float* __restrict__ W1,     // [H, NIN]
    const float* __restrict__ Wrec,   // [H, H]
    const float* __restrict__ W2,     // [2, H]
    const float* __restrict__ alpha,  // [H]
    const float* __restrict__ rho,    // [H]
    const float* __restrict__ beta_a, // [H]
    float* __restrict__ out)          // [B, 2]
{
    const int b2   = blockIdx.x;     // rows 2*b2, 2*b2+1
    const int tid  = threadIdx.x;
    const int wv   = tid >> 6;
    const int lane = tid & 63;
    const int lq   = lane >> 4;
    const int lr   = lane & 15;

    __shared__ __align__(16) unsigned short xlds[2][2][CH * XPAD]; // 53.2 KB
    __shared__ float spk_lds[H_];
    __shared__ int   flagLds[8];   // (chunk j -> slot j&3) * 2 + row
    __shared__ float red[16];
    unsigned short* Icold = &xlds[1][0][0];   // cold-path overlay (24 KB)

    // --- W1 fragments, NAMED, oma = 1-alpha folded in. Wave owns 4 h-tiles.
    bf16x8 wf00, wf01, wf02, wf10, wf11, wf12,
           wf20, wf21, wf22, wf30, wf31, wf32;
    float al0, al1, al2, al3, k0, k1, k2, k3;
#define LOADW(I, WA, WB, WC, ALV, KV) { \
    const int h_ = wv * 64 + (I) * 16 + lr; \
    const float av_ = alpha[h_]; ALV = av_; KV = pow16(av_); \
    const float om_ = 1.0f - av_; \
    const float* wr_ = W1 + h_ * NIN_ + lq * 8; \
    WA = packw(wr_, om_); WB = packw(wr_ + 32, om_); WC = packw(wr_ + 64, om_); }
    LOADW(0, wf00, wf01, wf02, al0, k0)
    LOADW(1, wf10, wf11, wf12, al1, k1)
    LOADW(2, wf20, wf21, wf22, al2, k2)
    LOADW(3, wf30, wf31, wf32, al3, k3)
#undef LOADW

    // x staging: all 512 threads; thread covers t_local = st, 12 floats/row.
    const float4* xb4A = reinterpret_cast<const float4*>(x + (size_t)(2 * b2)     * T_ * NIN_);
    const float4* xb4B = reinterpret_cast<const float4*>(x + (size_t)(2 * b2 + 1) * T_ * NIN_);
    const int st = tid >> 3, sq = tid & 7;
    // time-permuted row: row s*16+4q+j holds t_local = 16q+4s+j
    const int rwPerm = ((st & 15) >> 2) * 16 + (st >> 4) * 4 + (st & 3);
    float4 xrA0, xrA1, xrA2, xrB0, xrB1, xrB2;
    auto XLOADA = [&](int c) {
        int t = c * CH + st;
        if (t < T_) {
            const float4* p = xb4A + t * 24 + sq * 3;
            xrA0 = p[0]; xrA1 = p[1]; xrA2 = p[2];
        } else {
            xrA0 = make_float4(0.f, 0.f, 0.f, 0.f); xrA1 = xrA0; xrA2 = xrA0;
        }
    };
    auto XLOADB = [&](int c) {
        int t = c * CH + st;
        if (t < T_) {
            const float4* p = xb4B + t * 24 + sq * 3;
            xrB0 = p[0]; xrB1 = p[1]; xrB2 = p[2];
        } else {
            xrB0 = make_float4(0.f, 0.f, 0.f, 0.f); xrB1 = xrB0; xrB2 = xrB0;
        }
    };
    auto XWRITEA = [&](int buf, int row) {
        unsigned short* base = &xlds[buf][0][row * XPAD + sq * 12];
        *reinterpret_cast<uint2*>(base)     = make_uint2(pk2t(xrA0.x, xrA0.y), pk2t(xrA0.z, xrA0.w));
        *reinterpret_cast<uint2*>(base + 4) = make_uint2(pk2t(xrA1.x, xrA1.y), pk2t(xrA1.z, xrA1.w));
        *reinterpret_cast<uint2*>(base + 8) = make_uint2(pk2t(xrA2.x, xrA2.y), pk2t(xrA2.z, xrA2.w));
    };
    auto XWRITEB = [&](int buf, int row) {
        unsigned short* base = &xlds[buf][1][row * XPAD + sq * 12];
        *reinterpret_cast<uint2*>(base)     = make_uint2(pk2t(xrB0.x, xrB0.y), pk2t(xrB0.z, xrB0.w));
        *reinterpret_cast<uint2*>(base + 4) = make_uint2(pk2t(xrB1.x, xrB1.y), pk2t(xrB1.z, xrB1.w));
        *reinterpret_cast<uint2*>(base + 8) = make_uint2(pk2t(xrB2.x, xrB2.y), pk2t(xrB2.z, xrB2.w));
    };

    // per-row scan state
    float vA0 = 0.f, vA1 = 0.f, vA2 = 0.f, vA3 = 0.f;
    float vB0 = 0.f, vB1 = 0.f, vB2 = 0.f, vB3 = 0.f;
    float cAe0=0.f,cAe1=0.f,cAe2=0.f,cAe3=0.f, cAo0=0.f,cAo1=0.f,cAo2=0.f,cAo3=0.f;
    float cBe0=0.f,cBe1=0.f,cBe2=0.f,cBe3=0.f, cBo0=0.f,cBo1=0.f,cBo2=0.f,cBo3=0.f;
    float dA0=0.f,dA1=0.f,dA2=0.f,dA3=0.f, mA0=0.f,mA1=0.f,mA2=0.f,mA3=0.f;
    float dB0=0.f,dB1=0.f,dB2=0.f,dB3=0.f, mB0=0.f,mB1=0.f,mB2=0.f,mB3=0.f;

    if (tid < 8) flagLds[tid] = 0;
    XLOADA(0); XLOADB(0); XWRITEA(0, rwPerm); XWRITEB(0, rwPerm);
    XLOADA(1); XLOADB(1);
    __syncthreads();

    int coldF = -1;
    const bool bb0 = (lq & 1) != 0, bb1 = (lq & 2) != 0;

#define COMPOSE(DV, MV, ALV, KV, VV, TRIP) { \
        float A_  = DV; \
        float B_v = __shfl_xor(A_, 16); \
        float C_v = __shfl_xor(A_, 32); \
        float D_v = __shfl_xor(B_v, 32); \
        float x0_ = bb0 ? B_v : A_;  float x1_ = bb0 ? A_  : B_v; \
        float x2_ = bb0 ? D_v : C_v; float x3_ = bb0 ? C_v : D_v; \
        float e0_ = bb1 ? x2_ : x0_; float e1_ = bb1 ? x3_ : x1_; \
        float e2_ = bb1 ? x0_ : x2_; float e3_ = bb1 ? x1_ : x3_; \
        float w1_ = fmaf(KV, VV, e0_);  float w2_ = fmaf(KV, w1_, e1_); \
        float w3_ = fmaf(KV, w2_, e2_); float w4_ = fmaf(KV, w3_, e3_); \
        float vs_ = (lq == 0) ? VV : (lq == 1) ? w1_ : (lq == 2) ? w2_ : w3_; \
        TRIP = TRIP || ((MV + fabsf(vs_)) > 1.0f); \
        VV = w4_; }

#define MFMA_(XF, WA, WB, WC, WD) \
        a0 = __builtin_amdgcn_mfma_f32_16x16x32_bf16(XF, WA, a0, 0, 0, 0); \
        a1 = __builtin_amdgcn_mfma_f32_16x16x32_bf16(XF, WB, a1, 0, 0, 0); \
        a2 = __builtin_amdgcn_mfma_f32_16x16x32_bf16(XF, WC, a2, 0, 0, 0); \
        a3 = __builtin_amdgcn_mfma_f32_16x16x32_bf16(XF, WD, a3, 0, 0, 0);
#define FOLD_(AV, ALV, DV, MV) \
        DV = fmaf(ALV, DV, AV[0]); MV = fmaxf(MV, DV); \
        DV = fmaf(ALV, DV, AV[1]); MV = fmaxf(MV, DV); \
        DV = fmaf(ALV, DV, AV[2]); MV = fmaxf(MV, DV); \
        DV = fmaf(ALV, DV, AV[3]); MV = fmaxf(MV, DV);
#define SUBTILE(S, XB, D0,D1,D2,D3, M0,M1,M2,M3) { \
        f32x4 a0 = {0.f,0.f,0.f,0.f}, a1 = a0, a2 = a0, a3 = a0; \
        { bf16x8 xf = *reinterpret_cast<const bf16x8*>( \
              &(XB)[((S) * 16 + lr) * XPAD +  0 + lq * 8]); \
          MFMA_(xf, wf00, wf10, wf20, wf30) } \
        { bf16x8 xf = *reinterpret_cast<const bf16x8*>( \
              &(XB)[((S) * 16 + lr) * XPAD + 32 + lq * 8]); \
          MFMA_(xf, wf01, wf11, wf21, wf31) } \
        { bf16x8 xf = *reinterpret_cast<const bf16x8*>( \
              &(XB)[((S) * 16 + lr) * XPAD + 64 + lq * 8]); \
          MFMA_(xf, wf02, wf12, wf22, wf32) } \
        FOLD_(a0, al0, D0, M0) FOLD_(a1, al1, D1, M1) \
        FOLD_(a2, al2, D2, M2) FOLD_(a3, al3, D3, M3) }

    #pragma unroll 1
    for (int q = 0; q < NPH; ++q) {
        // flag(q-2): set during phase q-1, visible now. Read early, act late.
        int f = 0;
        if (q >= 2) {
            f = flagLds[((q - 2) & 3) * 2] | flagLds[((q - 2) & 3) * 2 + 1];
            if (tid == 0) {
                flagLds[((q - 2) & 3) * 2] = 0;
                flagLds[((q - 2) & 3) * 2 + 1] = 0;
            }
        }
        // checkpoint: v here == v_start(q-1) -> slot (q-1)&1
        if (((q - 1) & 1) == 0) {
            cAe0 = vA0; cAe1 = vA1; cAe2 = vA2; cAe3 = vA3;
            cBe0 = vB0; cBe1 = vB1; cBe2 = vB2; cBe3 = vB3;
        } else {
            cAo0 = vA0; cAo1 = vA1; cAo2 = vA2; cAo3 = vA3;
            cBo0 = vB0; cBo1 = vB1; cBo2 = vB2; cBo3 = vB3;
        }

        // --- compose chunk q-1, both rows.
        if (q >= 1) {
            bool tripA = false, tripB = false;
            COMPOSE(dA0, mA0, al0, k0, vA0, tripA)
            COMPOSE(dB0, mB0, al0, k0, vB0, tripB)
            COMPOSE(dA1, mA1, al1, k1, vA1, tripA)
            COMPOSE(dB1, mB1, al1, k1, vB1, tripB)
            COMPOSE(dA2, mA2, al2, k2, vA2, tripA)
            COMPOSE(dB2, mB2, al2, k2, vB2, tripB)
            COMPOSE(dA3, mA3, al3, k3, vA3, tripA)
            COMPOSE(dB3, mB3, al3, k3, vB3, tripB)
            if (tripA) flagLds[((q - 1) & 3) * 2] = 1;       // benign race
            if (tripB) flagLds[((q - 1) & 3) * 2 + 1] = 1;
        }

        // --- fold chunk q, both rows (independent chains interleaved).
        dA0 = 0.f; dA1 = 0.f; dA2 = 0.f; dA3 = 0.f;
        dB0 = 0.f; dB1 = 0.f; dB2 = 0.f; dB3 = 0.f;
        mA0 = -3.4e38f; mA1 = -3.4e38f; mA2 = -3.4e38f; mA3 = -3.4e38f;
        mB0 = -3.4e38f; mB1 = -3.4e38f; mB2 = -3.4e38f; mB3 = -3.4e38f;
        const unsigned short* xbA = xlds[q & 1][0];
        const unsigned short* xbB = xlds[q & 1][1];
        SUBTILE(0, xbA, dA0,dA1,dA2,dA3, mA0,mA1,mA2,mA3)
        SUBTILE(0, xbB, dB0,dB1,dB2,dB3, mB0,mB1,mB2,mB3)
        SUBTILE(1, xbA, dA0,dA1,dA2,dA3, mA0,mA1,mA2,mA3)
        SUBTILE(1, xbB, dB0,dB1,dB2,dB3, mB0,mB1,mB2,mB3)
        SUBTILE(2, xbA, dA0,dA1,dA2,dA3, mA0,mA1,mA2,mA3)
        SUBTILE(2, xbB, dB0,dB1,dB2,dB3, mB0,mB1,mB2,mB3)
        SUBTILE(3, xbA, dA0,dA1,dA2,dA3, mA0,mA1,mA2,mA3)
        SUBTILE(3, xbB, dB0,dB1,dB2,dB3, mB0,mB1,mB2,mB3)

        if (q + 1 < NPH) { XWRITEA((q + 1) & 1, rwPerm); XWRITEB((q + 1) & 1, rwPerm); }
        if (q + 2 < NPH) { XLOADA(q + 2); XLOADB(q + 2); }

        if (f) { coldF = q - 2; break; }   // uniform; phase q was speculative
        __syncthreads();                   // xlds[(q+1)&1] + flag(q-1) visible
    }

    // --- epilogue: chunks NPH-2 (flag set in phase NPH-1) and NPH-1.
    if (coldF < 0 &&
        (flagLds[((NPH - 2) & 3) * 2] | flagLds[((NPH - 2) & 3) * 2 + 1]) != 0)
        coldF = NPH - 2;
    if (coldF < 0) {
        // checkpoint v_start(NPH-1) -> slot (NPH-1)&1 (odd)
        cAo0 = vA0; cAo1 = vA1; cAo2 = vA2; cAo3 = vA3;
        cBo0 = vB0; cBo1 = vB1; cBo2 = vB2; cBo3 = vB3;
        bool tripA = false, tripB = false;
        COMPOSE(dA0, mA0, al0, k0, vA0, tripA)
        COMPOSE(dB0, mB0, al0, k0, vB0, tripB)
        COMPOSE(dA1, mA1, al1, k1, vA1, tripA)
        COMPOSE(dB1, mB1, al1, k1, vB1, tripB)
        COMPOSE(dA2, mA2, al2, k2, vA2, tripA)
        COMPOSE(dB2, mB2, al2, k2, vB2, tripB)
        COMPOSE(dA3, mA3, al3, k3, vA3, tripA)
        COMPOSE(dB3, mB3, al3, k3, vB3, tripB)
        // last chunk had 12 zero-input (decay-only) steps: * al^-12
        { float q2 = al0*al0, q4 = q2*q2; float c = q4 / k0; vA0 *= c; vB0 *= c; }
        { float q2 = al1*al1, q4 = q2*q2; float c = q4 / k1; vA1 *= c; vB1 *= c; }
        { float q2 = al2*al2, q4 = q2*q2; float c = q4 / k2; vA2 *= c; vB2 *= c; }
        { float q2 = al3*al3, q4 = q2*q2; float c = q4 / k3; vA3 *= c; vB3 *= c; }
        if (tripA) flagLds[((NPH - 1) & 3) * 2] = 1;
        if (tripB) flagLds[((NPH - 1) & 3) * 2 + 1] = 1;
        __syncthreads();
        if ((flagLds[((NPH - 1) & 3) * 2] | flagLds[((NPH - 1) & 3) * 2 + 1]) != 0)
            coldF = NPH - 1;
    }
#undef COMPOSE

    bool ex = false;
    float vexA = 0.f, vexB = 0.f;
    if (coldF >= 0) {
        // rollback BOTH rows to v_start(coldF) (slot coldF&1); a,spk == 0.
        // Exact re-run == speculative for a non-spiking row, so this is
        // correct even if only one row tripped.
        float vvA, vvB;
        if (coldF & 1) {
            vvA = (lq==0)?cAo0:(lq==1)?cAo1:(lq==2)?cAo2:cAo3;
            vvB = (lq==0)?cBo0:(lq==1)?cBo1:(lq==2)?cBo2:cBo3;
        } else {
            vvA = (lq==0)?cAe0:(lq==1)?cAe1:(lq==2)?cAe2:cAe3;
            vvB = (lq==0)?cBe0:(lq==1)?cBe1:(lq==2)?cBe2:cBe3;
        }
        const float alc  = alpha[tid];
        const float omac = 1.0f - alc;
        const float rhc  = rho[tid];
        const float bec  = beta_a[tid];
        #pragma unroll 1
        for (int row = 0; row < 2; ++row) {
            float vv = row ? vvB : vvA;
            float aa = 0.f, ss = 0.f;
            __syncthreads();
            spk_lds[tid] = 0.f;
            #pragma unroll 1
            for (int jj = coldF; jj < NPH; ++jj) {
                __syncthreads();
                if (row) { XLOADB(jj); } else { XLOADA(jj); }
                // identity-row restage of this row's x into xlds[0][0]
                {
                    unsigned short* base = &xlds[0][0][st * XPAD + sq * 12];
                    float4 r0 = row ? xrB0 : xrA0;
                    float4 r1 = row ? xrB1 : xrA1;
                    float4 r2 = row ? xrB2 : xrA2;
                    *reinterpret_cast<uint2*>(base)     = make_uint2(pk2t(r0.x, r0.y), pk2t(r0.z, r0.w));
                    *reinterpret_cast<uint2*>(base + 4) = make_uint2(pk2t(r1.x, r1.y), pk2t(r1.z, r1.w));
                    *reinterpret_cast<uint2*>(base + 8) = make_uint2(pk2t(r2.x, r2.y), pk2t(r2.z, r2.w));
                }
                __syncthreads();
                int remain = (jj == NPH - 1) ? LASTN : CH;
                #pragma unroll 1
                for (int s = 0; s < 4 && remain > 0; ++s) {
                    f32x4 c0 = {0.f,0.f,0.f,0.f}, c1 = c0, c2 = c0, c3 = c0;
                    #pragma unroll
                    for (int kb = 0; kb < 3; ++kb) {
                        bf16x8 xf = *reinterpret_cast<const bf16x8*>(
                            &xlds[0][0][(s * 16 + lr) * XPAD + kb * 32 + lq * 8]);
                        if (kb == 0) {
                            c0 = __builtin_amdgcn_mfma_f32_16x16x32_bf16(xf, wf00, c0, 0, 0, 0);
                            c1 = __builtin_amdgcn_mfma_f32_16x16x32_bf16(xf, wf10, c1, 0, 0, 0);
                            c2 = __builtin_amdgcn_mfma_f32_16x16x32_bf16(xf, wf20, c2, 0, 0, 0);
                            c3 = __builtin_amdgcn_mfma_f32_16x16x32_bf16(xf, wf30, c3, 0, 0, 0);
                        } else if (kb == 1) {
                            c0 = __builtin_amdgcn_mfma_f32_16x16x32_bf16(xf, wf01, c0, 0, 0, 0);
                            c1 = __builtin_amdgcn_mfma_f32_16x16x32_bf16(xf, wf11, c1, 0, 0, 0);
                            c2 = __builtin_amdgcn_mfma_f32_16x16x32_bf16(xf, wf21, c2, 0, 0, 0);
                            c3 = __builtin_amdgcn_mfma_f32_16x16x32_bf16(xf, wf31, c3, 0, 0, 0);
                        } else {
                            c0 = __builtin_amdgcn_mfma_f32_16x16x32_bf16(xf, wf02, c0, 0, 0, 0);
                            c1 = __builtin_amdgcn_mfma_f32_16x16x32_bf16(xf, wf12, c1, 0, 0, 0);
                            c2 = __builtin_amdgcn_mfma_f32_16x16x32_bf16(xf, wf22, c2, 0, 0, 0);
                            c3 = __builtin_amdgcn_mfma_f32_16x16x32_bf16(xf, wf32, c3, 0, 0, 0);
                        }
                    }
                    const int h0 = wv * 64 + lr;
                    *reinterpret_cast<uint2*>(&Icold[(h0     ) * PTC + lq * 4]) =
                        make_uint2(pk2(c0[0], c0[1]), pk2(c0[2], c0[3]));
                    *reinterpret_cast<uint2*>(&Icold[(h0 + 16) * PTC + lq * 4]) =
                        make_uint2(pk2(c1[0], c1[1]), pk2(c1[2], c1[3]));
                    *reinterpret_cast<uint2*>(&Icold[(h0 + 32) * PTC + lq * 4]) =
                        make_uint2(pk2(c2[0], c2[1]), pk2(c2[2], c2[3]));
                    *reinterpret_cast<uint2*>(&Icold[(h0 + 48) * PTC + lq * 4]) =
                        make_uint2(pk2(c3[0], c3[1]), pk2(c3[2], c3[3]));
                    __syncthreads();
                    int ns = remain < 16 ? remain : 16;
                    exact_steps(ns, &Icold[tid * PTC], spk_lds, Wrec, tid,
                                alc, omac, rhc, bec, vv, aa, ss);
                    remain -= ns;
                }
            }
            if (row) vexB = vv; else vexA = vv;
        }
        ex = true;
    }

    // Readout: out[b,n] = sum_h v_h * W2[n,h], rows A then B.
    #pragma unroll 1
    for (int row = 0; row < 2; ++row) {
        float p0, p1;
        if (ex) {
            float vex = row ? vexB : vexA;
            p0 = vex * W2[tid];
            p1 = vex * W2[H_ + tid];
        } else {
            p0 = 0.f; p1 = 0.f;
            if (lq == 0) {   // v replicated over lq; count each h once
                const int h0 = wv * 64 + lr;
                float u0 = row ? vB0 : vA0, u1 = row ? vB1 : vA1;
                float u2 = row ? vB2 : vA2, u3 = row ? vB3 : vA3;
                p0 = u0 * W2[h0]      + u1 * W2[h0 + 16]
                   + u2 * W2[h0 + 32] + u3 * W2[h0 + 48];
                p1 = u0 * W2[H_ + h0]      + u1 * W2[H_ + h0 + 16]
                   + u2 * W2[H_ + h0 + 32] + u3 * W2[H_ + h0 + 48];
            }
        }
        #pragma unroll
        for (int off = 32; off > 0; off >>= 1) {
            p0 += __shfl_down(p0, off, 64);
            p1 += __shfl_down(p1, off, 64);
        }
        __syncthreads();   // red[] free (prev row's readout done)
        if (lane == 0) { red[wv * 2] = p0; red[wv * 2 + 1] = p1; }
        __syncthreads();
        if (tid == 0) {
            float s0 = 0.f, s1 = 0.f;
            #pragma unroll
            for (int w8 = 0; w8 < 8; ++w8) { s0 += red[w8 * 2]; s1 += red[w8 * 2 + 1]; }
            out[(2 * b2 + row) * 2 + 0] = s0;
            out[(2 * b2 + row) * 2 + 1] = s1;
        }
    }
}

extern "C" void kernel_launch(void* const* d_in, const int* in_sizes, int n_in,
                              void* d_out, int out_size, void* d_ws, size_t ws_size,
                              hipStream_t stream) {
    const float* x      = (const float*)d_in[0];
    const float* W1     = (const float*)d_in[1];
    const float* Wrec   = (const float*)d_in[2];
    const float* W2     = (const float*)d_in[3];
    const float* alpha  = (const float*)d_in[4];
    const float* rho    = (const float*)d_in[5];
    const float* beta_a = (const float*)d_in[6];
    float* out = (float*)d_out;

    snn_dual2<<<dim3(B2_), dim3(512), 0, stream>>>(
        x, W1, Wrec, W2, alpha, rho, beta_a, out);
}